// Round 20
// baseline (79.547 us; speedup 1.0000x reference)
//
#include <hip/hip_runtime.h>
#include <hip/hip_bf16.h>

#define SEQ 2048
#define EMB 1024
#define NH 8
#define HD 64
#define DVH 128
#define LAMBDA_INIT 0.7836057665316245f
#define ONE_MINUS_LI 0.2163942334683755f
#define RMS_EPS 1e-5f
// 0.125 (1/sqrt(64)) * log2(e): folded into Q at the GEMM epilogue
#define QK_SCALE 0.18033688011112042f

typedef __attribute__((ext_vector_type(8))) short short8_t;
typedef __attribute__((ext_vector_type(4))) float f32x4;

__device__ __forceinline__ short f2bf(float f) {
    __hip_bfloat16 h = __float2bfloat16(f);
    return *reinterpret_cast<short*>(&h);
}
__device__ __forceinline__ unsigned pack2bf(float a, float b) {
    float2 f = {a, b};
    __hip_bfloat162 h = __float22bfloat162_rn(f);
    unsigned u;
    __builtin_memcpy(&u, &h, 4);
    return u;
}
__device__ __forceinline__ float bf2f(short s) {
    unsigned u = ((unsigned)(unsigned short)s) << 16;
    return __uint_as_float(u);
}
__device__ __forceinline__ float fast_exp2(float x) {
    float r;
    asm("v_exp_f32 %0, %1" : "=v"(r) : "v"(x));
    return r;
}
__device__ __forceinline__ void gload16(const void* g, void* l) {
    __builtin_amdgcn_global_load_lds((const __attribute__((address_space(1))) unsigned int*)g,
                                     (__attribute__((address_space(3))) unsigned int*)l, 16, 0, 0);
}

// ---------- merged prep: x->bf16 | weight transpose | lambda ----------
__global__ __launch_bounds__(256) void k_prep(const float* __restrict__ x, short* __restrict__ xb,
                                              const float* __restrict__ w0, const float* __restrict__ w1,
                                              const float* __restrict__ w2, const float* __restrict__ w3,
                                              short* __restrict__ o0, short* __restrict__ o1,
                                              short* __restrict__ o2, short* __restrict__ o3,
                                              const float* __restrict__ lq1, const float* __restrict__ lk1,
                                              const float* __restrict__ lq2, const float* __restrict__ lk2,
                                              float* __restrict__ lam) {
    const int bid = blockIdx.x;
    const int tid = threadIdx.x;
    if (bid < 1024) {
        int i = bid * 256 + tid;
        const float4* xv = (const float4*)x;
        float4 v0 = xv[i * 2];
        float4 v1 = xv[i * 2 + 1];
        unsigned u[4];
        u[0] = pack2bf(v0.x, v0.y);
        u[1] = pack2bf(v0.z, v0.w);
        u[2] = pack2bf(v1.x, v1.y);
        u[3] = pack2bf(v1.z, v1.w);
        short8_t r;
        __builtin_memcpy(&r, u, 16);
        *(short8_t*)(xb + i * 8) = r;
    } else if (bid < 2048) {
        int t = bid - 1024;
        int bz = t >> 8, by = (t >> 4) & 15, bx = t & 15;
        const float* w = bz == 0 ? w0 : bz == 1 ? w1 : bz == 2 ? w2 : w3;
        short* o = bz == 0 ? o0 : bz == 1 ? o1 : bz == 2 ? o2 : o3;
        __shared__ float tbuf[64][65];
        int r0 = by * 64, c0 = bx * 64;
        int col = tid & 63, rb = tid >> 6;
#pragma unroll
        for (int i = 0; i < 16; i++) {
            int row = rb + i * 4;
            tbuf[row][col] = w[(r0 + row) * EMB + c0 + col];
        }
        __syncthreads();
        const int col2 = (tid & 31) * 2;
        const int rb8 = tid >> 5;
#pragma unroll
        for (int i = 0; i < 8; i++) {
            int fr = rb8 + i * 8;
            unsigned u = pack2bf(tbuf[col2][fr], tbuf[col2 + 1][fr]);
            *(unsigned*)(o + (size_t)(c0 + fr) * EMB + r0 + col2) = u;
        }
    } else {
        if (tid < 64) {
            float p1 = lq1[tid] * lk1[tid], p2 = lq2[tid] * lk2[tid];
#pragma unroll
            for (int off = 32; off >= 1; off >>= 1) {
                p1 += __shfl_xor(p1, off);
                p2 += __shfl_xor(p2, off);
            }
            if (tid == 0) lam[0] = expf(p1) - expf(p2) + LAMBDA_INIT;
        }
    }
}

// ---------- tiled GEMM, LDS double-buffered (T3 2-phase), fused epilogues ----------
template <int MI, int NI, int OUTM>
__global__ __launch_bounds__(256) void k_gemm(const short* __restrict__ A,
                                              const short* __restrict__ B0,
                                              const short* __restrict__ B1,
                                              const short* __restrict__ B2,
                                              const float* __restrict__ cosT,
                                              const float* __restrict__ sinT,
                                              short* __restrict__ Cq, short* __restrict__ Ktl,
                                              short* __restrict__ Vtl, float* __restrict__ Cf) {
    constexpr int BM = MI * 32, BN = NI * 32, BK = 64;
    constexpr int STAGE_SZ = (BM + BN) * BK;
    constexpr int SH_EPI = (OUTM == 0) ? BM * 136 : 0;
    constexpr int SHSZ = (2 * STAGE_SZ > SH_EPI) ? 2 * STAGE_SZ : SH_EPI;
    __shared__ short SH[SHSZ];
    const int bn = blockIdx.x * BN;
    const int bm = blockIdx.y * BM;
    const int nsel = bn >> 10;
    const int nloc = bn & 1023;
    const short* Bt = nsel == 0 ? B0 : (nsel == 1 ? B1 : B2);
    const int tid = threadIdx.x;
    const int w = tid >> 6, l = tid & 63;
    const int lr = l & 15, lg = l >> 4;
    const int wm = (w >> 1) * (MI * 16), wn = (w & 1) * (NI * 16);
    const int lrow8 = l >> 3, lchunk = l & 7;
    const int schunk = (lchunk ^ lrow8) * 8;

    f32x4 acc[MI][NI];
#pragma unroll
    for (int mi = 0; mi < MI; mi++)
#pragma unroll
        for (int ni = 0; ni < NI; ni++) acc[mi][ni] = f32x4{0.f, 0.f, 0.f, 0.f};

#define STAGEIT(BUF, K0)                                                                      \
    {                                                                                         \
        short* Ab_ = SH + (BUF) * STAGE_SZ;                                                   \
        short* Bb_ = Ab_ + BM * BK;                                                           \
        _Pragma("unroll") for (int j = 0; j < BM / 32; j++) {                                 \
            int r0 = w * (BM / 4) + j * 8;                                                    \
            gload16(A + (size_t)(bm + r0 + lrow8) * EMB + (K0) + schunk, &Ab_[r0 * BK]);      \
        }                                                                                     \
        _Pragma("unroll") for (int j = 0; j < BN / 32; j++) {                                 \
            int r0 = w * (BN / 4) + j * 8;                                                    \
            gload16(Bt + (size_t)(nloc + r0 + lrow8) * EMB + (K0) + schunk, &Bb_[r0 * BK]);   \
        }                                                                                     \
    }

    STAGEIT(0, 0);
    __syncthreads();
#pragma unroll 1
    for (int t = 0; t < EMB / BK; ++t) {
        const int cur = t & 1;
        if (t + 1 < EMB / BK) STAGEIT(cur ^ 1, (t + 1) * BK);
        const short* Ab_ = SH + cur * STAGE_SZ;
        const short* Bb_ = Ab_ + BM * BK;
#pragma unroll
        for (int kk = 0; kk < 2; kk++) {
            const int pcs = (((kk << 2) + lg) ^ (lr & 7)) << 3;
            short8_t af[MI], bf[NI];
#pragma unroll
            for (int mi = 0; mi < MI; mi++)
                af[mi] = *(const short8_t*)&Ab_[(wm + mi * 16 + lr) * BK + pcs];
#pragma unroll
            for (int ni = 0; ni < NI; ni++)
                bf[ni] = *(const short8_t*)&Bb_[(wn + ni * 16 + lr) * BK + pcs];
#pragma unroll
            for (int mi = 0; mi < MI; mi++)
#pragma unroll
                for (int ni = 0; ni < NI; ni++)
                    acc[mi][ni] =
                        __builtin_amdgcn_mfma_f32_16x16x32_bf16(af[mi], bf[ni], acc[mi][ni], 0, 0, 0);
        }
        __syncthreads();
    }
#undef STAGEIT

    if (OUTM == 1) {
#pragma unroll
        for (int mi = 0; mi < MI; mi++)
#pragma unroll
            for (int ni = 0; ni < NI; ni++)
#pragma unroll
                for (int r = 0; r < 4; r++) {
                    int row = bm + wm + mi * 16 + lg * 4 + r;
                    int col = wn + ni * 16 + lr;
                    Cf[row * EMB + bn + col] = acc[mi][ni][r];
                }
        return;
    }
    const int hh = nloc >> 7;
    short* tile = SH;
    if (nsel < 2) {
#pragma unroll
        for (int mi = 0; mi < MI; mi++)
#pragma unroll
            for (int ni = 0; ni < NI; ni++) {
                const int c = wn + ni * 16 + lr;
                const int p = (c & 63) >> 1;
#pragma unroll
                for (int r = 0; r < 4; r++) {
                    const int row = wm + mi * 16 + lg * 4 + r;
                    const int grow = bm + row;
                    float v = acc[mi][ni][r];
                    float partner = __shfl_xor(v, 1);
                    float cs = cosT[grow * 32 + p], sn = sinT[grow * 32 + p];
                    float out = (lr & 1) ? (partner * sn + v * cs) : (v * cs - partner * sn);
                    if (nsel == 0)
                        Cq[((size_t)hh << 18) + (size_t)grow * 128 + c] = f2bf(out * QK_SCALE);
                    else
                        tile[row * 136 + c] = f2bf(out);
                }
            }
        if (nsel == 1) {
            __syncthreads();
            const int kb0 = blockIdx.y * (BM / 32);
#pragma unroll
            for (int i = 0; i < BM / 16; i++) {
                int flat = tid + i * 256;
                int kbi = flat >> 9, rest = flat & 511;
                int slot = rest >> 6, ln = rest & 63;
                int lqq = ln & 15;
                int comp = slot >> 2, tt = (slot >> 1) & 1, s = slot & 1;
                int lgg = ln >> 4;
                int row = kbi * 32 + tt * 16 + lqq;
                int fb = comp * 64 + s * 32 + lgg * 8;
                short8_t v = *(const short8_t*)&tile[row * 136 + fb];
                *(short8_t*)(Ktl + ((size_t)(hh * 64 + kb0 + kbi) * 8 + slot) * 512 + ln * 8) = v;
            }
        }
    } else {
#pragma unroll
        for (int mi = 0; mi < MI; mi++)
#pragma unroll
            for (int ni = 0; ni < NI; ni++) {
                const int c = wn + ni * 16 + lr;
#pragma unroll
                for (int r = 0; r < 4; r++) {
                    const int row = wm + mi * 16 + lg * 4 + r;
                    tile[row * 136 + c] = f2bf(acc[mi][ni][r]);
                }
            }
        __syncthreads();
        const int kb0 = blockIdx.y * (BM / 32);
#pragma unroll
        for (int i = 0; i < BM / 16; i++) {
            int flat = tid + i * 256;
            int kbi = flat >> 9, rest = flat & 511;
            int dt = rest >> 6, ln = rest & 63;
            int lgg = ln >> 4, lqq = ln & 15;
            short8_t v;
#pragma unroll
            for (int j = 0; j < 8; j++)
                v[j] = tile[(kbi * 32 + 16 * (j >> 2) + 4 * lgg + (j & 3)) * 136 + dt * 16 + lqq];
            *(short8_t*)(Vtl + ((size_t)(hh * 64 + kb0 + kbi) * 8 + dt) * 512 + ln * 8) = v;
        }
    }
}

// ---------- fused differential flash attention (R15 structure, lean merge) ----------
// Block = 32 q-rows x (2 comps x 4 k-splits) = 8 waves, reg-double-buffered
// K/V, 2 waves/SIMD (1 block/CU resident -> 2 scheduling rounds).
// Complementary pairing: round-1 block on CU c gets tile 63-(c>>3), round-2
// gets tile (c>>3) -> each CU totals exactly 65 kb-units. Merge epilogue:
// single-pass 4-way reduce (2 barriers/subtile instead of 4).
__global__ __launch_bounds__(512, 2) void k_attn(const short* __restrict__ Qh,
                                                 const short* __restrict__ Ktl,
                                                 const short* __restrict__ Vtl,
                                                 const float* __restrict__ lamp,
                                                 const float* __restrict__ subln,
                                                 short* __restrict__ Ab) {
    const int bid = blockIdx.x;
    const int h = bid & 7;
    const int tile = (bid < 256) ? (63 - (bid >> 3)) : ((bid - 256) >> 3);
    const int q0 = tile * 32;
    const int tid = threadIdx.x;
    const int w = tid >> 6, l = tid & 63;
    const int lq = l & 15, lg = l >> 4;
    const int comp = w >> 2, ks = w & 3;

    __shared__ __align__(16) float buf[2][3][16][132];  // ks=1,2,3 slots; slot0 reused for result
    __shared__ float LBp[2][4][16];

    const int nb = tile + 1;

    short8_t qf0[2], qf1[2];
    {
        const short* qp = Qh + ((size_t)h << 18) + (size_t)(q0 + lq) * 128 + (comp << 6) + lg * 8;
        qf0[0] = *(const short8_t*)(qp);
        qf0[1] = *(const short8_t*)(qp + 32);
        qf1[0] = *(const short8_t*)(qp + 16 * 128);
        qf1[1] = *(const short8_t*)(qp + 16 * 128 + 32);
    }
    short8_t vones;
#pragma unroll
    for (int j = 0; j < 8; j++) vones[j] = (short)0x3F80;  // bf16 1.0

    f32x4 zero4 = {0.f, 0.f, 0.f, 0.f};
    f32x4 o0[8], o1[8];
    f32x4 on0 = zero4, on1 = zero4;
#pragma unroll
    for (int dt = 0; dt < 8; dt++) {
        o0[dt] = zero4;
        o1[dt] = zero4;
    }

    short8_t vfA[8], vfB[8];
    short8_t kfA[2][2], kfB[2][2];

#define LOADKV(VF, KF, KB)                                                                  \
    {                                                                                       \
        const short* vtb = Vtl + (size_t)(h * 64 + (KB)) * 4096 + l * 8;                    \
        const short* ktb = Ktl + ((size_t)(h * 64 + (KB)) * 8 + comp * 4) * 512 + l * 8;    \
        _Pragma("unroll") for (int dt = 0; dt < 8; dt++) VF[dt] =                           \
            *(const short8_t*)(vtb + dt * 512);                                             \
        _Pragma("unroll") for (int tt = 0; tt < 2; tt++) {                                  \
            KF[tt][0] = *(const short8_t*)(ktb + (tt * 2) * 512);                           \
            KF[tt][1] = *(const short8_t*)(ktb + (tt * 2 + 1) * 512);                       \
        }                                                                                   \
    }

#define PROC(VF, KF, KB)                                                                     \
    {                                                                                        \
        const int k0p = (KB) * 32;                                                          \
        f32x4 s0[2], s1[2];                                                                  \
        _Pragma("unroll") for (int tt = 0; tt < 2; tt++) {                                   \
            s0[tt] = zero4;                                                                  \
            s0[tt] = __builtin_amdgcn_mfma_f32_16x16x32_bf16(KF[tt][0], qf0[0], s0[tt], 0, 0, 0); \
            s0[tt] = __builtin_amdgcn_mfma_f32_16x16x32_bf16(KF[tt][1], qf0[1], s0[tt], 0, 0, 0); \
            s1[tt] = zero4;                                                                  \
            s1[tt] = __builtin_amdgcn_mfma_f32_16x16x32_bf16(KF[tt][0], qf1[0], s1[tt], 0, 0, 0); \
            s1[tt] = __builtin_amdgcn_mfma_f32_16x16x32_bf16(KF[tt][1], qf1[1], s1[tt], 0, 0, 0); \
        }                                                                                    \
        float p0[8], p1[8];                                                                  \
        _Pragma("unroll") for (int tt = 0; tt < 2; tt++)                                     \
            _Pragma("unroll") for (int r = 0; r < 4; r++) {                                  \
                p0[tt * 4 + r] = s0[tt][r];                                                  \
                p1[tt * 4 + r] = s1[tt][r];                                                  \
            }                                                                                \
        if (k0p + 31 > q0) {                                                                 \
            _Pragma("unroll") for (int tt = 0; tt < 2; tt++)                                 \
                _Pragma("unroll") for (int r = 0; r < 4; r++) {                              \
                    int kk = k0p + tt * 16 + lg * 4 + r;                                     \
                    if (kk > q0 + lq) p0[tt * 4 + r] = -1e30f;                               \
                    if (kk > q0 + 16 + lq) p1[tt * 4 + r] = -1e30f;                          \
                }                                                                            \
        }                                                                                    \
        _Pragma("unroll") for (int i = 0; i < 8; i++) {                                      \
            p0[i] = fast_exp2(p0[i]);                                                        \
            p1[i] = fast_exp2(p1[i]);                                                        \
        }                                                                                    \
        unsigned pu0[4], pu1[4];                                                             \
        _Pragma("unroll") for (int pr = 0; pr < 4; pr++) {                                   \
            pu0[pr] = pack2bf(p0[2 * pr], p0[2 * pr + 1]);                                   \
            pu1[pr] = pack2bf(p1[2 * pr], p1[2 * pr + 1]);                                   \
        }                                                                                    \
        short8_t pa0, pa1;                                                                   \
        __builtin_memcpy(&pa0, pu0, 16);                                                     \
        __builtin_memcpy(&pa1, pu1, 16);                                                     \
        on0 = __builtin_amdgcn_mfma_f32_16x16x32_bf16(pa0, vones, on0, 0, 0, 0);             \
        on1 = __builtin_amdgcn_mfma_f32_16x16x32_bf16(pa1, vones, on1, 0, 0, 0);             \
        _Pragma("unroll") for (int dt = 0; dt < 8; dt++) {                                   \
            o0[dt] = __builtin_amdgcn_mfma_f32_16x16x32_bf16(pa0, VF[dt], o0[dt], 0, 0, 0);  \
            o1[dt] = __builtin_amdgcn_mfma_f32_16x16x32_bf16(pa1, VF[dt], o1[dt], 0, 0, 0);  \
        }                                                                                    \
    }

    if (ks < nb) LOADKV(vfA, kfA, ks);
    for (int kb = ks; kb < nb; kb += 8) {
        const bool hb = (kb + 4) < nb;
        if (hb) LOADKV(vfB, kfB, kb + 4);
        PROC(vfA, kfA, kb);
        if (hb) {
            if (kb + 8 < nb) LOADKV(vfA, kfA, kb + 8);
            PROC(vfB, kfB, kb + 4);
        }
    }
#undef LOADKV
#undef PROC

    // ---- two sequential 16-row merges, single-pass 4-way reduce ----
    // on[r] holds l[q = lg*4+r] (replicated across the 16 lanes of group lg).
#pragma unroll 1
    for (int sub = 0; sub < 2; sub++) {
        const f32x4* o = sub ? o1 : o0;
        const f32x4 on = sub ? on1 : on0;
        const int qbase = q0 + sub * 16;
        if (sub) __syncthreads();  // protect buf reuse from previous sub's readers
        if (lq == 0) {
#pragma unroll
            for (int r = 0; r < 4; r++) LBp[comp][ks][lg * 4 + r] = on[r];
        }
        if (ks >= 1) {
#pragma unroll
            for (int dt = 0; dt < 8; dt++)
#pragma unroll
                for (int r = 0; r < 4; r++) buf[comp][ks - 1][lg * 4 + r][dt * 16 + lq] = o[dt][r];
        }
        __syncthreads();
        if (ks == 0) {
            f32x4 oacc[8];
#pragma unroll
            for (int dt = 0; dt < 8; dt++)
#pragma unroll
                for (int r = 0; r < 4; r++)
                    oacc[dt][r] = o[dt][r] + buf[comp][0][lg * 4 + r][dt * 16 + lq] +
                                  buf[comp][1][lg * 4 + r][dt * 16 + lq] +
                                  buf[comp][2][lg * 4 + r][dt * 16 + lq];
            float lacc = LBp[comp][0][lq] + LBp[comp][1][lq] + LBp[comp][2][lq] + LBp[comp][3][lq];
            const float cs = comp ? lamp[0] : 1.f;
            float inv[4];
#pragma unroll
            for (int r = 0; r < 4; r++) inv[r] = cs / __shfl(lacc, lg * 4 + r);
#pragma unroll
            for (int dt = 0; dt < 8; dt++)
#pragma unroll
                for (int r = 0; r < 4; r++)
                    buf[comp][0][lg * 4 + r][dt * 16 + lq] = oacc[dt][r] * inv[r];
        }
        __syncthreads();
        if (tid < 128) {
            const int row = tid >> 3;
            const int c0 = (tid & 7) * 16;
            float a[16], ss = 0.f;
#pragma unroll
            for (int j = 0; j < 16; j++) {
                a[j] = buf[0][0][row][c0 + j] - buf[1][0][row][c0 + j];
                ss += a[j] * a[j];
            }
            ss += __shfl_xor(ss, 1);
            ss += __shfl_xor(ss, 2);
            ss += __shfl_xor(ss, 4);
            const float sc = rsqrtf(ss * (1.0f / 128.0f) + RMS_EPS) * ONE_MINUS_LI;
            short8_t r8;
#pragma unroll
            for (int j = 0; j < 8; j++) r8[j] = f2bf(a[j] * sc * subln[c0 + j]);
            *(short8_t*)(Ab + (size_t)(qbase + row) * EMB + h * DVH + c0) = r8;
#pragma unroll
            for (int j = 0; j < 8; j++) r8[j] = f2bf(a[8 + j] * sc * subln[c0 + 8 + j]);
            *(short8_t*)(Ab + (size_t)(qbase + row) * EMB + h * DVH + c0 + 8) = r8;
        }
    }
}

extern "C" void kernel_launch(void* const* d_in, const int* in_sizes, int n_in,
                              void* d_out, int out_size, void* d_ws, size_t ws_size,
                              hipStream_t stream) {
    const float* x = (const float*)d_in[0];
    const float* cosT = (const float*)d_in[1];
    const float* sinT = (const float*)d_in[2];
    const float* wq = (const float*)d_in[3];
    const float* wk = (const float*)d_in[4];
    const float* wv = (const float*)d_in[5];
    const float* wo = (const float*)d_in[6];
    const float* lq1 = (const float*)d_in[7];
    const float* lk1 = (const float*)d_in[8];
    const float* lq2 = (const float*)d_in[9];
    const float* lk2 = (const float*)d_in[10];
    const float* subln = (const float*)d_in[11];
    float* out = (float*)d_out;
    char* ws = (char*)d_ws;
    const size_t MB = 1 << 20;
    short* xb = (short*)(ws);
    short* wqt = (short*)(ws + 4 * MB);
    short* wkt = (short*)(ws + 6 * MB);
    short* wvt = (short*)(ws + 8 * MB);
    short* wot = (short*)(ws + 10 * MB);
    short* Qh = (short*)(ws + 12 * MB);
    short* Vtl = (short*)(ws + 20 * MB);
    short* Ktl = (short*)(ws + 24 * MB);
    short* Ab = (short*)(ws + 28 * MB);
    float* lam = (float*)(ws + 32 * MB);

    k_prep<<<2049, 256, 0, stream>>>(x, xb, wq, wk, wv, wo, wqt, wkt, wvt, wot, lq1, lk1, lq2,
                                     lk2, lam);
    k_gemm<2, 4, 0><<<dim3(24, 32), 256, 0, stream>>>(xb, wqt, wkt, wvt, cosT, sinT, Qh, Ktl,
                                                      Vtl, nullptr);
    k_attn<<<512, 512, 0, stream>>>(Qh, Ktl, Vtl, lam, subln, Ab);
    k_gemm<2, 2, 1><<<dim3(16, 32), 256, 0, stream>>>(Ab, wot, wot, wot, nullptr, nullptr,
                                                      nullptr, nullptr, nullptr, out);
}

// Round 21
// 74.600 us; speedup vs baseline: 1.0663x; 1.0663x over previous
//
#include <hip/hip_runtime.h>
#include <hip/hip_bf16.h>

#define SEQ 2048
#define EMB 1024
#define NH 8
#define HD 64
#define DVH 128
#define LAMBDA_INIT 0.7836057665316245f
#define ONE_MINUS_LI 0.2163942334683755f
#define RMS_EPS 1e-5f
// 0.125 (1/sqrt(64)) * log2(e): folded into Q at the GEMM epilogue
#define QK_SCALE 0.18033688011112042f

typedef __attribute__((ext_vector_type(8))) short short8_t;
typedef __attribute__((ext_vector_type(4))) float f32x4;

__device__ __forceinline__ short f2bf(float f) {
    __hip_bfloat16 h = __float2bfloat16(f);
    return *reinterpret_cast<short*>(&h);
}
__device__ __forceinline__ unsigned pack2bf(float a, float b) {
    float2 f = {a, b};
    __hip_bfloat162 h = __float22bfloat162_rn(f);
    unsigned u;
    __builtin_memcpy(&u, &h, 4);
    return u;
}
__device__ __forceinline__ float bf2f(short s) {
    unsigned u = ((unsigned)(unsigned short)s) << 16;
    return __uint_as_float(u);
}
__device__ __forceinline__ float fast_exp2(float x) {
    float r;
    asm("v_exp_f32 %0, %1" : "=v"(r) : "v"(x));
    return r;
}
__device__ __forceinline__ void gload16(const void* g, void* l) {
    __builtin_amdgcn_global_load_lds((const __attribute__((address_space(1))) unsigned int*)g,
                                     (__attribute__((address_space(3))) unsigned int*)l, 16, 0, 0);
}

// ---------- merged prep: x->bf16 | weight transpose | lambda ----------
__global__ __launch_bounds__(256) void k_prep(const float* __restrict__ x, short* __restrict__ xb,
                                              const float* __restrict__ w0, const float* __restrict__ w1,
                                              const float* __restrict__ w2, const float* __restrict__ w3,
                                              short* __restrict__ o0, short* __restrict__ o1,
                                              short* __restrict__ o2, short* __restrict__ o3,
                                              const float* __restrict__ lq1, const float* __restrict__ lk1,
                                              const float* __restrict__ lq2, const float* __restrict__ lk2,
                                              float* __restrict__ lam) {
    const int bid = blockIdx.x;
    const int tid = threadIdx.x;
    if (bid < 1024) {
        // x -> bf16, 8 elements/thread, 16B stores
        int i = bid * 256 + tid;
        const float4* xv = (const float4*)x;
        float4 v0 = xv[i * 2];
        float4 v1 = xv[i * 2 + 1];
        unsigned u[4];
        u[0] = pack2bf(v0.x, v0.y);
        u[1] = pack2bf(v0.z, v0.w);
        u[2] = pack2bf(v1.x, v1.y);
        u[3] = pack2bf(v1.z, v1.w);
        short8_t r;
        __builtin_memcpy(&r, u, 16);
        *(short8_t*)(xb + i * 8) = r;
    } else if (bid < 2048) {
        int t = bid - 1024;
        int bz = t >> 8, by = (t >> 4) & 15, bx = t & 15;
        const float* w = bz == 0 ? w0 : bz == 1 ? w1 : bz == 2 ? w2 : w3;
        short* o = bz == 0 ? o0 : bz == 1 ? o1 : bz == 2 ? o2 : o3;
        __shared__ float tbuf[64][65];
        int r0 = by * 64, c0 = bx * 64;
        int col = tid & 63, rb = tid >> 6;
#pragma unroll
        for (int i = 0; i < 16; i++) {
            int row = rb + i * 4;
            tbuf[row][col] = w[(r0 + row) * EMB + c0 + col];
        }
        __syncthreads();
        // packed u32 writes: thread handles column pair (col2, col2+1)
        const int col2 = (tid & 31) * 2;
        const int rb8 = tid >> 5;  // 0..7
#pragma unroll
        for (int i = 0; i < 8; i++) {
            int fr = rb8 + i * 8;
            unsigned u = pack2bf(tbuf[col2][fr], tbuf[col2 + 1][fr]);
            *(unsigned*)(o + (size_t)(c0 + fr) * EMB + r0 + col2) = u;
        }
    } else {
        if (tid < 64) {
            float p1 = lq1[tid] * lk1[tid], p2 = lq2[tid] * lk2[tid];
#pragma unroll
            for (int off = 32; off >= 1; off >>= 1) {
                p1 += __shfl_xor(p1, off);
                p2 += __shfl_xor(p2, off);
            }
            if (tid == 0) lam[0] = expf(p1) - expf(p2) + LAMBDA_INIT;
        }
    }
}

// ---------- tiled GEMM, LDS double-buffered (T3 2-phase), fused epilogues ----------
template <int MI, int NI, int OUTM>
__global__ __launch_bounds__(256) void k_gemm(const short* __restrict__ A,
                                              const short* __restrict__ B0,
                                              const short* __restrict__ B1,
                                              const short* __restrict__ B2,
                                              const float* __restrict__ cosT,
                                              const float* __restrict__ sinT,
                                              short* __restrict__ Cq, short* __restrict__ Ktl,
                                              short* __restrict__ Vtl, float* __restrict__ Cf) {
    constexpr int BM = MI * 32, BN = NI * 32, BK = 64;
    constexpr int STAGE_SZ = (BM + BN) * BK;
    constexpr int SH_EPI = (OUTM == 0) ? BM * 136 : 0;
    constexpr int SHSZ = (2 * STAGE_SZ > SH_EPI) ? 2 * STAGE_SZ : SH_EPI;
    __shared__ short SH[SHSZ];
    const int bn = blockIdx.x * BN;
    const int bm = blockIdx.y * BM;
    const int nsel = bn >> 10;
    const int nloc = bn & 1023;
    const short* Bt = nsel == 0 ? B0 : (nsel == 1 ? B1 : B2);
    const int tid = threadIdx.x;
    const int w = tid >> 6, l = tid & 63;
    const int lr = l & 15, lg = l >> 4;
    const int wm = (w >> 1) * (MI * 16), wn = (w & 1) * (NI * 16);
    const int lrow8 = l >> 3, lchunk = l & 7;
    const int schunk = (lchunk ^ lrow8) * 8;

    f32x4 acc[MI][NI];
#pragma unroll
    for (int mi = 0; mi < MI; mi++)
#pragma unroll
        for (int ni = 0; ni < NI; ni++) acc[mi][ni] = f32x4{0.f, 0.f, 0.f, 0.f};

#define STAGEIT(BUF, K0)                                                                      \
    {                                                                                         \
        short* Ab_ = SH + (BUF) * STAGE_SZ;                                                   \
        short* Bb_ = Ab_ + BM * BK;                                                           \
        _Pragma("unroll") for (int j = 0; j < BM / 32; j++) {                                 \
            int r0 = w * (BM / 4) + j * 8;                                                    \
            gload16(A + (size_t)(bm + r0 + lrow8) * EMB + (K0) + schunk, &Ab_[r0 * BK]);      \
        }                                                                                     \
        _Pragma("unroll") for (int j = 0; j < BN / 32; j++) {                                 \
            int r0 = w * (BN / 4) + j * 8;                                                    \
            gload16(Bt + (size_t)(nloc + r0 + lrow8) * EMB + (K0) + schunk, &Bb_[r0 * BK]);   \
        }                                                                                     \
    }

    STAGEIT(0, 0);
    __syncthreads();
#pragma unroll 1
    for (int t = 0; t < EMB / BK; ++t) {
        const int cur = t & 1;
        if (t + 1 < EMB / BK) STAGEIT(cur ^ 1, (t + 1) * BK);
        const short* Ab_ = SH + cur * STAGE_SZ;
        const short* Bb_ = Ab_ + BM * BK;
#pragma unroll
        for (int kk = 0; kk < 2; kk++) {
            const int pcs = (((kk << 2) + lg) ^ (lr & 7)) << 3;
            short8_t af[MI], bf[NI];
#pragma unroll
            for (int mi = 0; mi < MI; mi++)
                af[mi] = *(const short8_t*)&Ab_[(wm + mi * 16 + lr) * BK + pcs];
#pragma unroll
            for (int ni = 0; ni < NI; ni++)
                bf[ni] = *(const short8_t*)&Bb_[(wn + ni * 16 + lr) * BK + pcs];
#pragma unroll
            for (int mi = 0; mi < MI; mi++)
#pragma unroll
                for (int ni = 0; ni < NI; ni++)
                    acc[mi][ni] =
                        __builtin_amdgcn_mfma_f32_16x16x32_bf16(af[mi], bf[ni], acc[mi][ni], 0, 0, 0);
        }
        __syncthreads();
    }
#undef STAGEIT

    if (OUTM == 1) {
#pragma unroll
        for (int mi = 0; mi < MI; mi++)
#pragma unroll
            for (int ni = 0; ni < NI; ni++)
#pragma unroll
                for (int r = 0; r < 4; r++) {
                    int row = bm + wm + mi * 16 + lg * 4 + r;
                    int col = wn + ni * 16 + lr;
                    Cf[row * EMB + bn + col] = acc[mi][ni][r];
                }
        return;
    }
    const int hh = nloc >> 7;
    short* tile = SH;
    if (nsel < 2) {
#pragma unroll
        for (int mi = 0; mi < MI; mi++)
#pragma unroll
            for (int ni = 0; ni < NI; ni++) {
                const int c = wn + ni * 16 + lr;
                const int p = (c & 63) >> 1;
#pragma unroll
                for (int r = 0; r < 4; r++) {
                    const int row = wm + mi * 16 + lg * 4 + r;
                    const int grow = bm + row;
                    float v = acc[mi][ni][r];
                    float partner = __shfl_xor(v, 1);
                    float cs = cosT[grow * 32 + p], sn = sinT[grow * 32 + p];
                    float out = (lr & 1) ? (partner * sn + v * cs) : (v * cs - partner * sn);
                    if (nsel == 0)
                        Cq[((size_t)hh << 18) + (size_t)grow * 128 + c] = f2bf(out * QK_SCALE);
                    else
                        tile[row * 136 + c] = f2bf(out);
                }
            }
        if (nsel == 1) {
            __syncthreads();
            const int kb0 = blockIdx.y * (BM / 32);
#pragma unroll
            for (int i = 0; i < BM / 16; i++) {
                int flat = tid + i * 256;
                int kbi = flat >> 9, rest = flat & 511;
                int slot = rest >> 6, ln = rest & 63;
                int lqq = ln & 15;
                int comp = slot >> 2, tt = (slot >> 1) & 1, s = slot & 1;
                int lgg = ln >> 4;
                int row = kbi * 32 + tt * 16 + lqq;
                int fb = comp * 64 + s * 32 + lgg * 8;
                short8_t v = *(const short8_t*)&tile[row * 136 + fb];
                *(short8_t*)(Ktl + ((size_t)(hh * 64 + kb0 + kbi) * 8 + slot) * 512 + ln * 8) = v;
            }
        }
    } else {
#pragma unroll
        for (int mi = 0; mi < MI; mi++)
#pragma unroll
            for (int ni = 0; ni < NI; ni++) {
                const int c = wn + ni * 16 + lr;
#pragma unroll
                for (int r = 0; r < 4; r++) {
                    const int row = wm + mi * 16 + lg * 4 + r;
                    tile[row * 136 + c] = f2bf(acc[mi][ni][r]);
                }
            }
        __syncthreads();
        const int kb0 = blockIdx.y * (BM / 32);
#pragma unroll
        for (int i = 0; i < BM / 16; i++) {
            int flat = tid + i * 256;
            int kbi = flat >> 9, rest = flat & 511;
            int dt = rest >> 6, ln = rest & 63;
            int lgg = ln >> 4, lqq = ln & 15;
            short8_t v;
#pragma unroll
            for (int j = 0; j < 8; j++)
                v[j] = tile[(kbi * 32 + 16 * (j >> 2) + 4 * lgg + (j & 3)) * 136 + dt * 16 + lqq];
            *(short8_t*)(Vtl + ((size_t)(hh * 64 + kb0 + kbi) * 8 + dt) * 512 + ln * 8) = v;
        }
    }
}

// ---------- fused differential flash attention (R15 structure) ----------
// Block = 32 q-rows x (2 comps x 4 k-splits) = 8 waves, reg-double-buffered
// K/V, 2 waves/SIMD. QK_SCALE pre-folded into Q, l = P*ones via MFMA pipe.
// No max-tracking, no LDS in the loop, no barriers in the loop.
__global__ __launch_bounds__(512, 2) void k_attn(const short* __restrict__ Qh,
                                                 const short* __restrict__ Ktl,
                                                 const short* __restrict__ Vtl,
                                                 const float* __restrict__ lamp,
                                                 const float* __restrict__ subln,
                                                 short* __restrict__ Ab) {
    const int bid = blockIdx.x;
    const int h = bid & 7;
    const int tile = 63 - (bid >> 3);  // longest first
    const int q0 = tile * 32;
    const int tid = threadIdx.x;
    const int w = tid >> 6, l = tid & 63;
    const int lq = l & 15, lg = l >> 4;
    const int comp = w >> 2, ks = w & 3;

    __shared__ __align__(16) float buf[2][2][16][132];
    __shared__ float LBp[2][4][16];

    const int nb = tile + 1;

    short8_t qf0[2], qf1[2];
    {
        const short* qp = Qh + ((size_t)h << 18) + (size_t)(q0 + lq) * 128 + (comp << 6) + lg * 8;
        qf0[0] = *(const short8_t*)(qp);
        qf0[1] = *(const short8_t*)(qp + 32);
        qf1[0] = *(const short8_t*)(qp + 16 * 128);
        qf1[1] = *(const short8_t*)(qp + 16 * 128 + 32);
    }
    short8_t vones;
#pragma unroll
    for (int j = 0; j < 8; j++) vones[j] = (short)0x3F80;  // bf16 1.0

    f32x4 zero4 = {0.f, 0.f, 0.f, 0.f};
    f32x4 o0[8], o1[8];
    f32x4 on0 = zero4, on1 = zero4;  // l accumulators (via ones-MFMA)
#pragma unroll
    for (int dt = 0; dt < 8; dt++) {
        o0[dt] = zero4;
        o1[dt] = zero4;
    }

    short8_t vfA[8], vfB[8];
    short8_t kfA[2][2], kfB[2][2];

#define LOADKV(VF, KF, KB)                                                                  \
    {                                                                                       \
        const short* vtb = Vtl + (size_t)(h * 64 + (KB)) * 4096 + l * 8;                    \
        const short* ktb = Ktl + ((size_t)(h * 64 + (KB)) * 8 + comp * 4) * 512 + l * 8;    \
        _Pragma("unroll") for (int dt = 0; dt < 8; dt++) VF[dt] =                           \
            *(const short8_t*)(vtb + dt * 512);                                             \
        _Pragma("unroll") for (int tt = 0; tt < 2; tt++) {                                  \
            KF[tt][0] = *(const short8_t*)(ktb + (tt * 2) * 512);                           \
            KF[tt][1] = *(const short8_t*)(ktb + (tt * 2 + 1) * 512);                       \
        }                                                                                   \
    }

#define PROC(VF, KF, KB)                                                                     \
    {                                                                                        \
        const int k0p = (KB) * 32;                                                          \
        f32x4 s0[2], s1[2];                                                                  \
        _Pragma("unroll") for (int tt = 0; tt < 2; tt++) {                                   \
            s0[tt] = zero4;                                                                  \
            s0[tt] = __builtin_amdgcn_mfma_f32_16x16x32_bf16(KF[tt][0], qf0[0], s0[tt], 0, 0, 0); \
            s0[tt] = __builtin_amdgcn_mfma_f32_16x16x32_bf16(KF[tt][1], qf0[1], s0[tt], 0, 0, 0); \
            s1[tt] = zero4;                                                                  \
            s1[tt] = __builtin_amdgcn_mfma_f32_16x16x32_bf16(KF[tt][0], qf1[0], s1[tt], 0, 0, 0); \
            s1[tt] = __builtin_amdgcn_mfma_f32_16x16x32_bf16(KF[tt][1], qf1[1], s1[tt], 0, 0, 0); \
        }                                                                                    \
        float p0[8], p1[8];                                                                  \
        _Pragma("unroll") for (int tt = 0; tt < 2; tt++)                                     \
            _Pragma("unroll") for (int r = 0; r < 4; r++) {                                  \
                p0[tt * 4 + r] = s0[tt][r];                                                  \
                p1[tt * 4 + r] = s1[tt][r];                                                  \
            }                                                                                \
        if (k0p + 31 > q0) {                                                                 \
            _Pragma("unroll") for (int tt = 0; tt < 2; tt++)                                 \
                _Pragma("unroll") for (int r = 0; r < 4; r++) {                              \
                    int kk = k0p + tt * 16 + lg * 4 + r;                                     \
                    if (kk > q0 + lq) p0[tt * 4 + r] = -1e30f;                               \
                    if (kk > q0 + 16 + lq) p1[tt * 4 + r] = -1e30f;                          \
                }                                                                            \
        }                                                                                    \
        _Pragma("unroll") for (int i = 0; i < 8; i++) {                                      \
            p0[i] = fast_exp2(p0[i]);                                                        \
            p1[i] = fast_exp2(p1[i]);                                                        \
        }                                                                                    \
        unsigned pu0[4], pu1[4];                                                             \
        _Pragma("unroll") for (int pr = 0; pr < 4; pr++) {                                   \
            pu0[pr] = pack2bf(p0[2 * pr], p0[2 * pr + 1]);                                   \
            pu1[pr] = pack2bf(p1[2 * pr], p1[2 * pr + 1]);                                   \
        }                                                                                    \
        short8_t pa0, pa1;                                                                   \
        __builtin_memcpy(&pa0, pu0, 16);                                                     \
        __builtin_memcpy(&pa1, pu1, 16);                                                     \
        on0 = __builtin_amdgcn_mfma_f32_16x16x32_bf16(pa0, vones, on0, 0, 0, 0);             \
        on1 = __builtin_amdgcn_mfma_f32_16x16x32_bf16(pa1, vones, on1, 0, 0, 0);             \
        _Pragma("unroll") for (int dt = 0; dt < 8; dt++) {                                   \
            o0[dt] = __builtin_amdgcn_mfma_f32_16x16x32_bf16(pa0, VF[dt], o0[dt], 0, 0, 0);  \
            o1[dt] = __builtin_amdgcn_mfma_f32_16x16x32_bf16(pa1, VF[dt], o1[dt], 0, 0, 0);  \
        }                                                                                    \
    }

    if (ks < nb) LOADKV(vfA, kfA, ks);
    for (int kb = ks; kb < nb; kb += 8) {
        const bool hb = (kb + 4) < nb;
        if (hb) LOADKV(vfB, kfB, kb + 4);
        PROC(vfA, kfA, kb);
        if (hb) {
            if (kb + 8 < nb) LOADKV(vfA, kfA, kb + 8);
            PROC(vfB, kfB, kb + 4);
        }
    }
#undef LOADKV
#undef PROC

    // ---- two sequential 16-row merges (sub = 0 then 1) ----
#pragma unroll 1
    for (int sub = 0; sub < 2; sub++) {
        const f32x4* o = sub ? o1 : o0;
        const f32x4 on = sub ? on1 : on0;
        const int qbase = q0 + sub * 16;
        if (sub) __syncthreads();
        if (lq == 0) {
#pragma unroll
            for (int r = 0; r < 4; r++) LBp[comp][ks][lg * 4 + r] = on[r];
        }
        if (ks >= 2) {
#pragma unroll
            for (int dt = 0; dt < 8; dt++)
#pragma unroll
                for (int r = 0; r < 4; r++) buf[comp][ks - 2][lg * 4 + r][dt * 16 + lq] = o[dt][r];
        }
        __syncthreads();
        f32x4 oacc[8];
        float lacc = 0.f;
        if (ks < 2) {
#pragma unroll
            for (int dt = 0; dt < 8; dt++)
#pragma unroll
                for (int r = 0; r < 4; r++)
                    oacc[dt][r] = o[dt][r] + buf[comp][ks][lg * 4 + r][dt * 16 + lq];
            lacc = LBp[comp][ks][lq] + LBp[comp][ks + 2][lq];
        }
        __syncthreads();
        if (ks == 1) {
#pragma unroll
            for (int dt = 0; dt < 8; dt++)
#pragma unroll
                for (int r = 0; r < 4; r++) buf[comp][0][lg * 4 + r][dt * 16 + lq] = oacc[dt][r];
            if (l < 16) LBp[comp][1][l] = lacc;
        }
        __syncthreads();
        if (ks == 0) {
#pragma unroll
            for (int dt = 0; dt < 8; dt++)
#pragma unroll
                for (int r = 0; r < 4; r++) oacc[dt][r] += buf[comp][0][lg * 4 + r][dt * 16 + lq];
            lacc += LBp[comp][1][lq];
            const float cs = comp ? lamp[0] : 1.f;
            float inv[4];
#pragma unroll
            for (int r = 0; r < 4; r++) inv[r] = cs / __shfl(lacc, lg * 4 + r);
#pragma unroll
            for (int dt = 0; dt < 8; dt++)
#pragma unroll
                for (int r = 0; r < 4; r++)
                    buf[comp][1][lg * 4 + r][dt * 16 + lq] = oacc[dt][r] * inv[r];
        }
        __syncthreads();
        if (tid < 128) {
            const int row = tid >> 3;
            const int c0 = (tid & 7) * 16;
            float a[16], ss = 0.f;
#pragma unroll
            for (int j = 0; j < 16; j++) {
                a[j] = buf[0][1][row][c0 + j] - buf[1][1][row][c0 + j];
                ss += a[j] * a[j];
            }
            ss += __shfl_xor(ss, 1);
            ss += __shfl_xor(ss, 2);
            ss += __shfl_xor(ss, 4);
            const float sc = rsqrtf(ss * (1.0f / 128.0f) + RMS_EPS) * ONE_MINUS_LI;
            short8_t r8;
#pragma unroll
            for (int j = 0; j < 8; j++) r8[j] = f2bf(a[j] * sc * subln[c0 + j]);
            *(short8_t*)(Ab + (size_t)(qbase + row) * EMB + h * DVH + c0) = r8;
#pragma unroll
            for (int j = 0; j < 8; j++) r8[j] = f2bf(a[8 + j] * sc * subln[c0 + 8 + j]);
            *(short8_t*)(Ab + (size_t)(qbase + row) * EMB + h * DVH + c0 + 8) = r8;
        }
    }
}

extern "C" void kernel_launch(void* const* d_in, const int* in_sizes, int n_in,
                              void* d_out, int out_size, void* d_ws, size_t ws_size,
                              hipStream_t stream) {
    const float* x = (const float*)d_in[0];
    const float* cosT = (const float*)d_in[1];
    const float* sinT = (const float*)d_in[2];
    const float* wq = (const float*)d_in[3];
    const float* wk = (const float*)d_in[4];
    const float* wv = (const float*)d_in[5];
    const float* wo = (const float*)d_in[6];
    const float* lq1 = (const float*)d_in[7];
    const float* lk1 = (const float*)d_in[8];
    const float* lq2 = (const float*)d_in[9];
    const float* lk2 = (const float*)d_in[10];
    const float* subln = (const float*)d_in[11];
    float* out = (float*)d_out;
    char* ws = (char*)d_ws;
    const size_t MB = 1 << 20;
    short* xb = (short*)(ws);
    short* wqt = (short*)(ws + 4 * MB);
    short* wkt = (short*)(ws + 6 * MB);
    short* wvt = (short*)(ws + 8 * MB);
    short* wot = (short*)(ws + 10 * MB);
    short* Qh = (short*)(ws + 12 * MB);
    short* Vtl = (short*)(ws + 20 * MB);
    short* Ktl = (short*)(ws + 24 * MB);
    short* Ab = (short*)(ws + 28 * MB);
    float* lam = (float*)(ws + 32 * MB);

    k_prep<<<2049, 256, 0, stream>>>(x, xb, wq, wk, wv, wo, wqt, wkt, wvt, wot, lq1, lk1, lq2,
                                     lk2, lam);
    k_gemm<2, 4, 0><<<dim3(24, 32), 256, 0, stream>>>(xb, wqt, wkt, wvt, cosT, sinT, Qh, Ktl,
                                                      Vtl, nullptr);
    k_attn<<<512, 512, 0, stream>>>(Qh, Ktl, Vtl, lam, subln, Ab);
    k_gemm<2, 2, 1><<<dim3(16, 32), 256, 0, stream>>>(Ab, wot, wot, wot, nullptr, nullptr,
                                                      nullptr, nullptr, nullptr, out);
}